// Round 7
// baseline (365.657 us; speedup 1.0000x reference)
//
#include <hip/hip_runtime.h>
#include <stdint.h>

typedef unsigned short u16;
typedef unsigned int u32;
typedef __attribute__((ext_vector_type(8))) short bf16x8;
typedef __attribute__((ext_vector_type(4))) float f32x4;

// ---------- helpers ----------
// GROUND TRUTH (R2-R4/R8/R9 pass vs R5-R7 NaN): inputs fp32, output fp32.
// Intermediates bf16 (absmax 0.0039 << 0.0123 threshold).
__device__ __forceinline__ float bf2f(u32 u) {
    union { u32 i; float f; } v; v.i = u << 16; return v.f;
}
__device__ __forceinline__ u16 f2bf(float f) {
    u32 x = __float_as_uint(f);
    return (u16)((x + 0x7fffu + ((x >> 16) & 1u)) >> 16);
}
__device__ __forceinline__ float wred_sum(float v) {
#pragma unroll
    for (int o = 32; o > 0; o >>= 1) v += __shfl_xor(v, o, 64);
    return v;
}
// pack 8 f32 (two float4) -> bf16x8 (same RNE as before; bit-identical results)
__device__ __forceinline__ bf16x8 cvt8(float4 a, float4 b) {
    union { uint4 u; bf16x8 v; } t;
    t.u.x = (u32)f2bf(a.x) | ((u32)f2bf(a.y) << 16);
    t.u.y = (u32)f2bf(a.z) | ((u32)f2bf(a.w) << 16);
    t.u.z = (u32)f2bf(b.x) | ((u32)f2bf(b.y) << 16);
    t.u.w = (u32)f2bf(b.z) | ((u32)f2bf(b.w) << 16);
    return t.v;
}
// 16B bf16x8 load from a u16 base + element offset (global or LDS) (proven R8/R9)
__device__ __forceinline__ bf16x8 ld16B(const u16* p, size_t off) {
    union { uint4 u; bf16x8 b; } t; t.u = *(const uint4*)(p + off); return t.b;
}
// B-fragment DIRECT from global bf16 weight matrix [128 x ldk], row-major.
// Same lane->element mapping as the R4-proven LDS ldB, with global stride.
// Weights are L2-resident (320KB, re-read by all blocks) -> ~200cy hit latency,
// hidden by barrier-free scheduling.
__device__ __forceinline__ bf16x8 ldBg(const u16* __restrict__ W, int ldk, int koff,
                                       int ks, int ct, int l16, int quad) {
    return ld16B(W, (size_t)(ct * 16 + l16) * ldk + koff + ks * 32 + quad * 8);
}

// ---------- one-time weight f32 -> bf16 conversion (concatenated dst) ----------
__global__ void k_cvtw(const float* __restrict__ s0, const float* __restrict__ s1,
                       const float* __restrict__ s2, const float* __restrict__ s3,
                       u16* __restrict__ d, int n0, int n1, int n2, int n3) {
    int i = (blockIdx.x * 256 + threadIdx.x) * 8;
    int t = i;
    const float* s;
    if (t < n0) s = s0 + t;
    else if ((t -= n0) < n1) s = s1 + t;
    else if ((t -= n1) < n2) s = s2 + t;
    else if ((t -= n2) < n3) s = s3 + t;
    else return;
    float4 a = *(const float4*)s, b = *(const float4*)(s + 4);
    uint4 v;
    v.x = (u32)f2bf(a.x) | ((u32)f2bf(a.y) << 16);
    v.y = (u32)f2bf(a.z) | ((u32)f2bf(a.w) << 16);
    v.z = (u32)f2bf(b.x) | ((u32)f2bf(b.y) << 16);
    v.w = (u32)f2bf(b.z) | ((u32)f2bf(b.w) << 16);
    *(uint4*)(d + i) = v;
}

// ---------- CSR build (R8/R9 verbatim, proven) ----------
__global__ void k_zero(int* __restrict__ p, int n) {
    int i = blockIdx.x * 256 + threadIdx.x;
    if (i < n) p[i] = 0;
}
__global__ void k_hist(const int* __restrict__ dst, int E, int* __restrict__ deg) {
    int e = blockIdx.x * 256 + threadIdx.x;
    if (e < E) atomicAdd(&deg[dst[e]], 1);
}
__global__ __launch_bounds__(1024) void k_scanA(const int* __restrict__ deg, int n,
                                                int* __restrict__ out, int* __restrict__ bsum) {
    __shared__ int wsum[16];
    int t = threadIdx.x, w = t >> 6, lane = t & 63;
    int i0 = blockIdx.x * 4096 + t * 4;
    int4 v = make_int4(0, 0, 0, 0);
    if (i0 + 3 < n) v = *(const int4*)&deg[i0];
    else {
        if (i0 < n)     v.x = deg[i0];
        if (i0 + 1 < n) v.y = deg[i0 + 1];
        if (i0 + 2 < n) v.z = deg[i0 + 2];
    }
    int tsum = v.x + v.y + v.z + v.w;
    int s = tsum;
#pragma unroll
    for (int o = 1; o < 64; o <<= 1) { int u = __shfl_up(s, o, 64); if (lane >= o) s += u; }
    if (lane == 63) wsum[w] = s;
    __syncthreads();
    if (w == 0 && lane < 16) {
        int ws = wsum[lane];
#pragma unroll
        for (int o = 1; o < 16; o <<= 1) { int u = __shfl_up(ws, o, 64); if (lane >= o) ws += u; }
        wsum[lane] = ws;
    }
    __syncthreads();
    int woff = (w == 0) ? 0 : wsum[w - 1];
    int p = woff + s - tsum;
    if (i0 + 3 < n) {
        int4 o4; o4.x = p; o4.y = p + v.x; o4.z = p + v.x + v.y; o4.w = p + v.x + v.y + v.z;
        *(int4*)&out[i0] = o4;
    } else {
        int pp = p;
        if (i0 < n)     { out[i0] = pp;     pp += v.x; }
        if (i0 + 1 < n) { out[i0 + 1] = pp; pp += v.y; }
        if (i0 + 2 < n) { out[i0 + 2] = pp; }
    }
    if (t == 0) bsum[blockIdx.x] = wsum[15];
}
__global__ void k_scanB(int* __restrict__ bsum, int nb, int* __restrict__ total) {
    int lane = threadIdx.x;
    int v = (lane < nb) ? bsum[lane] : 0;
    int s = v;
#pragma unroll
    for (int o = 1; o < 64; o <<= 1) { int u = __shfl_up(s, o, 64); if (lane >= o) s += u; }
    if (lane < nb) bsum[lane] = s - v;
    if (lane == 63) total[0] = s;
}
__global__ void k_scanC(int* __restrict__ rowptr, int* __restrict__ cursor,
                        const int* __restrict__ boff, int n) {
    int i = blockIdx.x * 256 + threadIdx.x;
    if (i < n) {
        int r = rowptr[i] + boff[i >> 12];
        rowptr[i] = r; cursor[i] = r;
    }
}
__global__ void k_scatter(const int* __restrict__ srcp, const int* __restrict__ dstp, int E,
                          int* __restrict__ cursor, int* __restrict__ col) {
    int e = blockIdx.x * 256 + threadIdx.x;
    if (e < E) {
        int p = atomicAdd(&cursor[dstp[e]], 1);
        col[p] = srcp[e];
    }
}

// ---------- fused: input proj + prelu0 + conv1 lin + att scalars ----------
// v7: ZERO barriers. R6 post-mortem: 6 variants of the load path all pinned at
// 46-54us -> the block-wide vmcnt(0)+barrier convoy per chunk is the invariant,
// not load micro-structure. Weights are L2-hot (320KB bf16) -> read B-fragments
// DIRECTLY from global per lane; no shared weight tile, no __syncthreads at all.
// Each wave streams independently; compiler schedules loads across the whole
// body. Phase-2 h-tile is per-wave-private LDS (within-wave ds RAW needs only
// lgkmcnt, auto-inserted). LDS 17KB/block -> occupancy no longer LDS-capped.
__global__ __launch_bounds__(256) void k_fused1(
    const float* __restrict__ x, const float* __restrict__ numx, const float* __restrict__ numm,
    const float* __restrict__ txt, const float* __restrict__ txtm,
    const float* __restrict__ numw, const float* __restrict__ numb,
    const float* __restrict__ txtb, const float* __restrict__ nodeb,
    const float* __restrict__ pa,
    const u16* __restrict__ txtwb, const u16* __restrict__ nodewb, const u16* __restrict__ w1b,
    const float* __restrict__ atts, const float* __restrict__ attd,
    u16* __restrict__ xh, float* __restrict__ asrc, float* __restrict__ adst) {
    __shared__ u16 sh[4][16 * 136];         // per-wave h-tile only
    int tid = threadIdx.x, w = tid >> 6, lane = tid & 63, quad = lane >> 4, l16 = lane & 15;
    int nb = blockIdx.x * 64 + w * 16;

    const float* trow = txt + (size_t)(nb + l16) * 384 + quad * 8;
    const float* xrow = x + (size_t)(nb + l16) * 128 + quad * 8;

    f32x4 acc[8];
#pragma unroll
    for (int ct = 0; ct < 8; ++ct) { f32x4 z = {0.f, 0.f, 0.f, 0.f}; acc[ct] = z; }

#define CHUNKG(Wp, ldk, koff, Ap)                                               \
    {                                                                           \
        const float* pA_ = (Ap);                                                \
        float4 A0 = *(const float4*)(pA_ + 0),  A1 = *(const float4*)(pA_ + 4);   \
        float4 A2 = *(const float4*)(pA_ + 32), A3 = *(const float4*)(pA_ + 36);  \
        float4 A4 = *(const float4*)(pA_ + 64), A5 = *(const float4*)(pA_ + 68);  \
        float4 A6 = *(const float4*)(pA_ + 96), A7 = *(const float4*)(pA_ + 100); \
        bf16x8 f0_ = cvt8(A0, A1), f1_ = cvt8(A2, A3);                          \
        bf16x8 f2_ = cvt8(A4, A5), f3_ = cvt8(A6, A7);                          \
        _Pragma("unroll")                                                       \
        for (int ct = 0; ct < 8; ++ct)                                          \
            acc[ct] = __builtin_amdgcn_mfma_f32_16x16x32_bf16(                  \
                f0_, ldBg(Wp, ldk, koff, 0, ct, l16, quad), acc[ct], 0, 0, 0);  \
        _Pragma("unroll")                                                       \
        for (int ct = 0; ct < 8; ++ct)                                          \
            acc[ct] = __builtin_amdgcn_mfma_f32_16x16x32_bf16(                  \
                f1_, ldBg(Wp, ldk, koff, 1, ct, l16, quad), acc[ct], 0, 0, 0);  \
        _Pragma("unroll")                                                       \
        for (int ct = 0; ct < 8; ++ct)                                          \
            acc[ct] = __builtin_amdgcn_mfma_f32_16x16x32_bf16(                  \
                f2_, ldBg(Wp, ldk, koff, 2, ct, l16, quad), acc[ct], 0, 0, 0);  \
        _Pragma("unroll")                                                       \
        for (int ct = 0; ct < 8; ++ct)                                          \
            acc[ct] = __builtin_amdgcn_mfma_f32_16x16x32_bf16(                  \
                f3_, ldBg(Wp, ldk, koff, 3, ct, l16, quad), acc[ct], 0, 0, 0);  \
    }

    CHUNKG(txtwb, 384, 0,   trow)
    CHUNKG(txtwb, 384, 128, trow + 128)
    CHUNKG(txtwb, 384, 256, trow + 256)
    // scale txt contribution by txt_mask
#pragma unroll
    for (int r = 0; r < 4; ++r) {
        float tm = txtm[nb + quad * 4 + r];
#pragma unroll
        for (int ct = 0; ct < 8; ++ct) acc[ct][r] *= tm;
    }
    CHUNKG(nodewb, 128, 0, xrow)
#undef CHUNKG

    // epilogue 1: num term + biases + prelu -> per-wave LDS h-tile [16][136] bf16
    float nm[4];
#pragma unroll
    for (int r = 0; r < 4; ++r) {
        int n = nb + quad * 4 + r;
        nm[r] = numx[n] * numm[n];
    }
    u16* shw = sh[w];
#pragma unroll
    for (int ct = 0; ct < 8; ++ct) {
        int c = ct * 16 + l16;
        float cw = numw[c];
        float cb = numb[c] + txtb[c] + nodeb[c];
        float pav = pa[c];
#pragma unroll
        for (int r = 0; r < 4; ++r) {
            float v = acc[ct][r] + nm[r] * cw + cb;
            v = v >= 0.f ? v : pav * v;
            shw[(quad * 4 + r) * 136 + c] = f2bf(v);
        }
    }
    // phase 2: xh = h0 @ W1^T. A from per-wave LDS (within-wave RAW: lgkmcnt only,
    // no barrier needed); B direct from global w1b.
    f32x4 a2[8];
#pragma unroll
    for (int ct = 0; ct < 8; ++ct) { f32x4 z = {0.f, 0.f, 0.f, 0.f}; a2[ct] = z; }
#pragma unroll
    for (int ks = 0; ks < 4; ++ks) {
        bf16x8 a0 = ld16B(shw, l16 * 136 + ks * 32 + quad * 8);
#pragma unroll
        for (int ct = 0; ct < 8; ++ct)
            a2[ct] = __builtin_amdgcn_mfma_f32_16x16x32_bf16(
                a0, ldBg(w1b, 128, 0, ks, ct, l16, quad), a2[ct], 0, 0, 0);
    }
    // epilogue 2: store xh + attention scalars (R9-proven reduction)
#pragma unroll
    for (int ct = 0; ct < 8; ++ct) {
        int c = ct * 16 + l16;
#pragma unroll
        for (int r = 0; r < 4; ++r)
            xh[(size_t)(nb + quad * 4 + r) * 128 + c] = f2bf(a2[ct][r]);
    }
    float as_[8], ad_[8];
#pragma unroll
    for (int ct = 0; ct < 8; ++ct) {
        int c = ct * 16 + l16;
        as_[ct] = atts[c];
        ad_[ct] = attd[c];
    }
#pragma unroll
    for (int hh = 0; hh < 4; ++hh) {
        float vs[4], vd[4];
#pragma unroll
        for (int r = 0; r < 4; ++r) {
            vs[r] = a2[2 * hh][r] * as_[2 * hh] + a2[2 * hh + 1][r] * as_[2 * hh + 1];
            vd[r] = a2[2 * hh][r] * ad_[2 * hh] + a2[2 * hh + 1][r] * ad_[2 * hh + 1];
        }
#pragma unroll
        for (int o = 1; o <= 8; o <<= 1) {
#pragma unroll
            for (int r = 0; r < 4; ++r) {
                vs[r] += __shfl_xor(vs[r], o, 64);
                vd[r] += __shfl_xor(vd[r], o, 64);
            }
        }
        if ((l16 >> 2) == hh) {
            int r = l16 & 3;
            float ss = (r == 0) ? vs[0] : (r == 1) ? vs[1] : (r == 2) ? vs[2] : vs[3];
            float dd = (r == 0) ? vd[0] : (r == 1) ? vd[1] : (r == 2) ? vd[2] : vd[3];
            int n = nb + quad * 4 + r;
            asrc[n * 4 + hh] = ss;
            adst[n * 4 + hh] = dd;
        }
    }
}

// ---------- xh = h @ W^T (MFMA) + attention scalars. v7: zero LDS, zero barriers ----------
__global__ __launch_bounds__(256) void k_xh(
    const u16* __restrict__ h, const u16* __restrict__ Wb,
    const float* __restrict__ att_s, const float* __restrict__ att_d,
    u16* __restrict__ xh, float* __restrict__ asrc, float* __restrict__ adst) {
    int tid = threadIdx.x;
    int w = tid >> 6, lane = tid & 63, quad = lane >> 4, l16 = lane & 15;
    int nb = blockIdx.x * 64 + w * 16;

    const u16* hrow = h + (size_t)(nb + l16) * 128 + quad * 8;
    bf16x8 A0 = ld16B(hrow, 0);
    bf16x8 A1 = ld16B(hrow, 32);
    bf16x8 A2 = ld16B(hrow, 64);
    bf16x8 A3 = ld16B(hrow, 96);
    f32x4 acc[8];
#pragma unroll
    for (int ct = 0; ct < 8; ++ct) { f32x4 z = {0.f, 0.f, 0.f, 0.f}; acc[ct] = z; }
#pragma unroll
    for (int ct = 0; ct < 8; ++ct)
        acc[ct] = __builtin_amdgcn_mfma_f32_16x16x32_bf16(
            A0, ldBg(Wb, 128, 0, 0, ct, l16, quad), acc[ct], 0, 0, 0);
#pragma unroll
    for (int ct = 0; ct < 8; ++ct)
        acc[ct] = __builtin_amdgcn_mfma_f32_16x16x32_bf16(
            A1, ldBg(Wb, 128, 0, 1, ct, l16, quad), acc[ct], 0, 0, 0);
#pragma unroll
    for (int ct = 0; ct < 8; ++ct)
        acc[ct] = __builtin_amdgcn_mfma_f32_16x16x32_bf16(
            A2, ldBg(Wb, 128, 0, 2, ct, l16, quad), acc[ct], 0, 0, 0);
#pragma unroll
    for (int ct = 0; ct < 8; ++ct)
        acc[ct] = __builtin_amdgcn_mfma_f32_16x16x32_bf16(
            A3, ldBg(Wb, 128, 0, 3, ct, l16, quad), acc[ct], 0, 0, 0);
#pragma unroll
    for (int ct = 0; ct < 8; ++ct) {
        int c = ct * 16 + l16;
#pragma unroll
        for (int r = 0; r < 4; ++r) {
            int n = nb + quad * 4 + r;
            xh[(size_t)n * 128 + c] = f2bf(acc[ct][r]);
        }
    }
    float as_[8], ad_[8];
#pragma unroll
    for (int ct = 0; ct < 8; ++ct) {
        int c = ct * 16 + l16;
        as_[ct] = att_s[c];
        ad_[ct] = att_d[c];
    }
#pragma unroll
    for (int hh = 0; hh < 4; ++hh) {
        float vs[4], vd[4];
#pragma unroll
        for (int r = 0; r < 4; ++r) {
            vs[r] = acc[2 * hh][r] * as_[2 * hh] + acc[2 * hh + 1][r] * as_[2 * hh + 1];
            vd[r] = acc[2 * hh][r] * ad_[2 * hh] + acc[2 * hh + 1][r] * ad_[2 * hh + 1];
        }
#pragma unroll
        for (int o = 1; o <= 8; o <<= 1) {
#pragma unroll
            for (int r = 0; r < 4; ++r) {
                vs[r] += __shfl_xor(vs[r], o, 64);
                vd[r] += __shfl_xor(vd[r], o, 64);
            }
        }
        if ((l16 >> 2) == hh) {
            int r = l16 & 3;
            float ss = (r == 0) ? vs[0] : (r == 1) ? vs[1] : (r == 2) ? vs[2] : vs[3];
            float dd = (r == 0) ? vd[0] : (r == 1) ? vd[1] : (r == 2) ? vd[2] : vd[3];
            int n = nb + quad * 4 + r;
            asrc[n * 4 + hh] = ss;
            adst[n * 4 + hh] = dd;
        }
    }
}

// ---------- per-dst softmax + aggregation + bias + LN + prelu (+ head) ----------
// v2: 8-deep unrolled serial gather (8 loads in flight; avg degree 16 -> 2 rounds).
__global__ __launch_bounds__(64) void k_agg(
    const u16* __restrict__ xh, const float* __restrict__ asrc, const float* __restrict__ adst,
    const int* __restrict__ rowptr, const int* __restrict__ col,
    const float* __restrict__ bias, const float* __restrict__ g, const float* __restrict__ b,
    const float* __restrict__ pa, u16* __restrict__ hnext,
    const float* __restrict__ outw, const float* __restrict__ outb, float* __restrict__ outy,
    int is_final) {
    __shared__ int   scol[64];
    __shared__ float scoef[64][4];
    int n = blockIdx.x, lane = threadIdx.x;
    int beg = rowptr[n], end = rowptr[n + 1];
    const float4* asrc4 = (const float4*)asrc;

    float4 adv = ((const float4*)adst)[n];
    float ad[4] = { adv.x, adv.y, adv.z, adv.w };
    float4 asv = asrc4[n];
    float els[4];
#pragma unroll
    for (int h = 0; h < 4; h++) {
        float a = ((const float*)&asv)[h] + ad[h];
        a = a >= 0.f ? a : 0.2f * a;
        els[h] = __expf(a);
    }
    int hh = lane >> 4;
    u32 vself = ((const u32*)(xh + (size_t)n * 128))[lane];
    float ac0[8], ac1[8];
#pragma unroll
    for (int q = 0; q < 8; ++q) { ac0[q] = 0.f; ac1[q] = 0.f; }
    ac0[0] = els[hh] * bf2f(vself & 0xffffu);
    ac1[0] = els[hh] * bf2f(vself >> 16);
    float l[4] = { 0.f, 0.f, 0.f, 0.f };

    for (int base = beg; base < end; base += 64) {
        int e = base + lane;
        int cnt = min(64, end - base);
        if (e < end) {
            int s = col[e];
            float4 av = asrc4[s];
            scol[lane] = s;
            float cf[4];
#pragma unroll
            for (int h = 0; h < 4; h++) {
                float a = ((const float*)&av)[h] + ad[h];
                a = a >= 0.f ? a : 0.2f * a;
                cf[h] = __expf(a);
                l[h] += cf[h];
            }
            *(float4*)scoef[lane] = make_float4(cf[0], cf[1], cf[2], cf[3]);
        }
        __syncthreads();
        int j = 0;
        for (; j + 7 < cnt; j += 8) {
            int ss[8]; float cc[8]; u32 vv[8];
#pragma unroll
            for (int q = 0; q < 8; ++q) { ss[q] = scol[j + q]; cc[q] = scoef[j + q][hh]; }
#pragma unroll
            for (int q = 0; q < 8; ++q) vv[q] = ((const u32*)(xh + (size_t)ss[q] * 128))[lane];
#pragma unroll
            for (int q = 0; q < 8; ++q) {
                ac0[q] += cc[q] * bf2f(vv[q] & 0xffffu);
                ac1[q] += cc[q] * bf2f(vv[q] >> 16);
            }
        }
        for (; j + 3 < cnt; j += 4) {
            int ss[4]; float cc[4]; u32 vv[4];
#pragma unroll
            for (int q = 0; q < 4; ++q) { ss[q] = scol[j + q]; cc[q] = scoef[j + q][hh]; }
#pragma unroll
            for (int q = 0; q < 4; ++q) vv[q] = ((const u32*)(xh + (size_t)ss[q] * 128))[lane];
#pragma unroll
            for (int q = 0; q < 4; ++q) {
                ac0[q] += cc[q] * bf2f(vv[q] & 0xffffu);
                ac1[q] += cc[q] * bf2f(vv[q] >> 16);
            }
        }
        for (; j < cnt; ++j) {
            int s0 = scol[j];
            float c0 = scoef[j][hh];
            u32 v0 = ((const u32*)(xh + (size_t)s0 * 128))[lane];
            ac0[0] += c0 * bf2f(v0 & 0xffffu);
            ac1[0] += c0 * bf2f(v0 >> 16);
        }
        __syncthreads();
    }
    float acc0 = 0.f, acc1 = 0.f;
#pragma unroll
    for (int q = 0; q < 8; ++q) { acc0 += ac0[q]; acc1 += ac1[q]; }

    float L[4];
#pragma unroll
    for (int h = 0; h < 4; h++) L[h] = wred_sum(l[h]) + els[h];
    float inv = 1.f / L[hh];
    acc0 *= inv;
    acc1 *= inv;

    int c0i = 2 * lane;
    float2 bi = *(const float2*)(bias + c0i);
    acc0 += bi.x; acc1 += bi.y;

    float mean = wred_sum(acc0 + acc1) * (1.f / 128.f);
    float d0 = acc0 - mean, d1 = acc1 - mean;
    float var = wred_sum(d0 * d0 + d1 * d1) * (1.f / 128.f);
    float rstd = rsqrtf(var + 1e-5f);
    float2 gg = *(const float2*)(g + c0i);
    float2 bb = *(const float2*)(b + c0i);
    float2 pp = *(const float2*)(pa + c0i);
    float y0 = d0 * rstd * gg.x + bb.x;
    float y1 = d1 * rstd * gg.y + bb.y;
    y0 = y0 >= 0.f ? y0 : pp.x * y0;
    y1 = y1 >= 0.f ? y1 : pp.y * y1;

    if (is_final) {
        float2 ow = *(const float2*)(outw + c0i);
        float dot = wred_sum(y0 * ow.x + y1 * ow.y);
        if (lane == 0) outy[n] = dot + outb[0];
    } else {
        ((u32*)(hnext + (size_t)n * 128))[lane] = (u32)f2bf(y0) | ((u32)f2bf(y1) << 16);
    }
}

// ---------- launch ----------
extern "C" void kernel_launch(void* const* d_in, const int* in_sizes, int n_in,
                              void* d_out, int out_size, void* d_ws, size_t ws_size,
                              hipStream_t stream) {
    const int N = in_sizes[2];          // num_mask has N elements
    const int E = in_sizes[5] / 2;      // edge_index is [2,E]

    const float* x      = (const float*)d_in[0];
    const float* numx   = (const float*)d_in[1];
    const float* numm   = (const float*)d_in[2];
    const float* txt    = (const float*)d_in[3];
    const float* txtm   = (const float*)d_in[4];
    const int*   ei     = (const int*)d_in[5];
    const float* numw   = (const float*)d_in[6];
    const float* numb   = (const float*)d_in[7];
    const float* txtw   = (const float*)d_in[8];
    const float* txtb   = (const float*)d_in[9];
    const float* nodew  = (const float*)d_in[10];
    const float* nodeb  = (const float*)d_in[11];
    const float* pa0    = (const float*)d_in[12];
    const float* conv1w = (const float*)d_in[13];
    const float* atts1  = (const float*)d_in[14];
    const float* attd1  = (const float*)d_in[15];
    const float* bias1  = (const float*)d_in[16];
    const float* g1     = (const float*)d_in[17];
    const float* b1     = (const float*)d_in[18];
    const float* pa1    = (const float*)d_in[19];
    const float* conv2w = (const float*)d_in[20];
    const float* atts2  = (const float*)d_in[21];
    const float* attd2  = (const float*)d_in[22];
    const float* bias2  = (const float*)d_in[23];
    const float* g2     = (const float*)d_in[24];
    const float* b2     = (const float*)d_in[25];
    const float* pa2    = (const float*)d_in[26];
    const float* outw   = (const float*)d_in[27];
    const float* outb   = (const float*)d_in[28];

    const int* srcp = ei;
    const int* dstp = ei + E;

    const int szTxtw = in_sizes[8];     // 128*384
    const int szNode = in_sizes[10];    // 128*128
    const int szW1   = in_sizes[13];
    const int szW2   = in_sizes[20];
    const int szWAll = szTxtw + szNode + szW1 + szW2;

    char* p = (char*)d_ws;
    auto alloc = [&](size_t bytes) -> void* {
        void* q = (void*)p;
        p += (bytes + 255) & ~(size_t)255;
        return q;
    };
    u16*   hA     = (u16*)alloc((size_t)N * 128 * 2);   // h1 (bf16)
    u16*   hB     = (u16*)alloc((size_t)N * 128 * 2);   // xh1 / xh2 (bf16)
    float* asrc   = (float*)alloc((size_t)N * 4 * 4);
    float* adst   = (float*)alloc((size_t)N * 4 * 4);
    int*   deg    = (int*)alloc((size_t)N * 4);
    int*   rowptr = (int*)alloc((size_t)(N + 1) * 4);
    int*   cursor = (int*)alloc((size_t)N * 4);
    int*   col    = (int*)alloc((size_t)E * 4);
    int*   bsum   = (int*)alloc(64 * 4);
    u16*   wbf    = (u16*)alloc((size_t)szWAll * 2);    // bf16 weights [txtw|nodew|W1|W2]

    u16* txtwb  = wbf;
    u16* nodewb = wbf + szTxtw;
    u16* w1b    = nodewb + szNode;
    u16* w2b    = w1b + szW1;

    // one-time weight conversion (ordered before k_fused1 on the stream)
    k_cvtw<<<(szWAll / 8 + 255) / 256, 256, 0, stream>>>(
        txtw, nodew, conv1w, conv2w, wbf, szTxtw, szNode, szW1, szW2);

    // CSR by dst (self-loops handled analytically in k_agg)
    const int nbScan = (N + 4095) / 4096;
    k_zero<<<(N + 255) / 256, 256, 0, stream>>>(deg, N);
    k_hist<<<(E + 255) / 256, 256, 0, stream>>>(dstp, E, deg);
    k_scanA<<<nbScan, 1024, 0, stream>>>(deg, N, rowptr, bsum);
    k_scanB<<<1, 64, 0, stream>>>(bsum, nbScan, rowptr + N);
    k_scanC<<<(N + 255) / 256, 256, 0, stream>>>(rowptr, cursor, bsum, N);
    k_scatter<<<(E + 255) / 256, 256, 0, stream>>>(srcp, dstp, E, cursor, col);

    const int gProj = N / 64;   // 625 for N=40000

    // layer 1: fused input proj + prelu0 + conv1 lin (h0 never touches HBM)
    k_fused1<<<gProj, 256, 0, stream>>>(x, numx, numm, txt, txtm, numw, numb,
                                        txtb, nodeb, pa0,
                                        txtwb, nodewb, w1b, atts1, attd1, hB, asrc, adst);
    k_agg<<<N, 64, 0, stream>>>(hB, asrc, adst, rowptr, col, bias1, g1, b1, pa1,
                                hA, nullptr, nullptr, nullptr, 0);

    // layer 2
    k_xh<<<gProj, 256, 0, stream>>>(hA, w2b, atts2, attd2, hB, asrc, adst);
    k_agg<<<N, 64, 0, stream>>>(hB, asrc, adst, rowptr, col, bias2, g2, b2, pa2,
                                nullptr, outw, outb, (float*)d_out, 1);
}

// Round 8
// 315.925 us; speedup vs baseline: 1.1574x; 1.1574x over previous
//
#include <hip/hip_runtime.h>
#include <stdint.h>

typedef unsigned short u16;
typedef unsigned int u32;
typedef __attribute__((ext_vector_type(8))) short bf16x8;
typedef __attribute__((ext_vector_type(4))) float f32x4;

// ---------- helpers ----------
// GROUND TRUTH (R2-R4/R8/R9 pass vs R5-R7 NaN): inputs fp32, output fp32.
// Intermediates bf16 (absmax 0.0039 << 0.0123 threshold).
__device__ __forceinline__ float bf2f(u32 u) {
    union { u32 i; float f; } v; v.i = u << 16; return v.f;
}
__device__ __forceinline__ u16 f2bf(float f) {
    u32 x = __float_as_uint(f);
    return (u16)((x + 0x7fffu + ((x >> 16) & 1u)) >> 16);
}
__device__ __forceinline__ float wred_sum(float v) {
#pragma unroll
    for (int o = 32; o > 0; o >>= 1) v += __shfl_xor(v, o, 64);
    return v;
}
// pack 8 f32 (two float4) -> bf16x8 (same RNE as before; bit-identical results)
__device__ __forceinline__ bf16x8 cvt8(float4 a, float4 b) {
    union { uint4 u; bf16x8 v; } t;
    t.u.x = (u32)f2bf(a.x) | ((u32)f2bf(a.y) << 16);
    t.u.y = (u32)f2bf(a.z) | ((u32)f2bf(a.w) << 16);
    t.u.z = (u32)f2bf(b.x) | ((u32)f2bf(b.y) << 16);
    t.u.w = (u32)f2bf(b.z) | ((u32)f2bf(b.w) << 16);
    return t.v;
}
// A-fragment from bf16 row (global or LDS) (proven R8/R9)
__device__ __forceinline__ bf16x8 ld16B(const u16* p, size_t off) {
    union { uint4 u; bf16x8 b; } t; t.u = *(const uint4*)(p + off); return t.b;
}
// async 16B global->LDS (zero VGPR round-trip). size must be literal 16.
__device__ __forceinline__ void glds16(const void* g, void* l) {
    __builtin_amdgcn_global_load_lds(
        (const __attribute__((address_space(1))) void*)g,
        (__attribute__((address_space(3))) void*)l, 16, 0, 0);
}
// stage one [128 x 128] bf16 weight chunk into LINEAR LDS tile via global_load_lds.
// Rule #21: glds dst is wave-uniform base + lane*16 (linear) -> swizzle the SOURCE:
// physical 16B-slot s of row r holds source slot s ^ (r&7).  (R4-proven)
__device__ __forceinline__ void stageW_glds(const u16* __restrict__ W, int ldk, int koff,
                                            u16* swl, int tid) {
    int w64 = tid >> 6;
#pragma unroll
    for (int it = 0; it < 8; ++it) {
        int row = it * 16 + (tid >> 4);       // LDS row this thread's 16B lands in
        int sphys = tid & 15;                 // physical 16B slot within the row
        int ssrc = sphys ^ (row & 7);         // source slot (inverse swizzle)
        const u16* g = W + (size_t)row * ldk + koff + ssrc * 8;
        u16* dst = swl + (size_t)(it * 256 + w64 * 64) * 8;   // wave-uniform base
        glds16(g, dst);
    }
}
// B-fragment read from linear+swizzled LDS weight tile [128][128]  (R4-proven)
__device__ __forceinline__ bf16x8 ldBx(const u16* swl, int ct, int ks, int l16, int quad) {
    int row = ct * 16 + l16;
    int slot = (ks * 4 + quad) ^ (row & 7);
    union { uint4 u; bf16x8 b; } t;
    t.u = *(const uint4*)&swl[row * 128 + slot * 8];
    return t.b;
}
// stage a per-wave [16 rows x 128 f32] A-tile into LDS via glds, COALESCED source.
// Same rule-#21 pattern: linear dst (lane*16B), source slot = phys ^ (row&7).
__device__ __forceinline__ void stageA_glds(const float* __restrict__ Ab, int ldk, int koff,
                                            float* sAw, int lane) {
#pragma unroll
    for (int it = 0; it < 8; ++it) {
        int rl = it * 2 + (lane >> 5);            // local row 0..15
        int sl = (lane & 31) ^ (rl & 7);          // source 16B-slot (inverse swizzle)
        const float* g = Ab + (size_t)rl * ldk + koff + sl * 4;
        glds16(g, sAw + it * 256);                // wave-uniform base + lane*16B
    }
}

// ---------- one-time weight f32 -> bf16 conversion + deg zeroing (merged) ----------
// v8: k_zero folded in (independent bounds-checked writes; one fewer launch).
__global__ void k_cvtw(const float* __restrict__ s0, const float* __restrict__ s1,
                       const float* __restrict__ s2, const float* __restrict__ s3,
                       u16* __restrict__ d, int n0, int n1, int n2, int n3,
                       int* __restrict__ deg, int N) {
    int tix = blockIdx.x * 256 + threadIdx.x;
    if (tix < N) deg[tix] = 0;
    int i = tix * 8;
    int t = i;
    const float* s;
    if (t < n0) s = s0 + t;
    else if ((t -= n0) < n1) s = s1 + t;
    else if ((t -= n1) < n2) s = s2 + t;
    else if ((t -= n2) < n3) s = s3 + t;
    else return;
    float4 a = *(const float4*)s, b = *(const float4*)(s + 4);
    uint4 v;
    v.x = (u32)f2bf(a.x) | ((u32)f2bf(a.y) << 16);
    v.y = (u32)f2bf(a.z) | ((u32)f2bf(a.w) << 16);
    v.z = (u32)f2bf(b.x) | ((u32)f2bf(b.y) << 16);
    v.w = (u32)f2bf(b.z) | ((u32)f2bf(b.w) << 16);
    *(uint4*)(d + i) = v;
}

// ---------- CSR build (R8/R9 verbatim, proven) ----------
__global__ void k_hist(const int* __restrict__ dst, int E, int* __restrict__ deg) {
    int e = blockIdx.x * 256 + threadIdx.x;
    if (e < E) atomicAdd(&deg[dst[e]], 1);
}
__global__ __launch_bounds__(1024) void k_scanA(const int* __restrict__ deg, int n,
                                                int* __restrict__ out, int* __restrict__ bsum) {
    __shared__ int wsum[16];
    int t = threadIdx.x, w = t >> 6, lane = t & 63;
    int i0 = blockIdx.x * 4096 + t * 4;
    int4 v = make_int4(0, 0, 0, 0);
    if (i0 + 3 < n) v = *(const int4*)&deg[i0];
    else {
        if (i0 < n)     v.x = deg[i0];
        if (i0 + 1 < n) v.y = deg[i0 + 1];
        if (i0 + 2 < n) v.z = deg[i0 + 2];
    }
    int tsum = v.x + v.y + v.z + v.w;
    int s = tsum;
#pragma unroll
    for (int o = 1; o < 64; o <<= 1) { int u = __shfl_up(s, o, 64); if (lane >= o) s += u; }
    if (lane == 63) wsum[w] = s;
    __syncthreads();
    if (w == 0 && lane < 16) {
        int ws = wsum[lane];
#pragma unroll
        for (int o = 1; o < 16; o <<= 1) { int u = __shfl_up(ws, o, 64); if (lane >= o) ws += u; }
        wsum[lane] = ws;
    }
    __syncthreads();
    int woff = (w == 0) ? 0 : wsum[w - 1];
    int p = woff + s - tsum;
    if (i0 + 3 < n) {
        int4 o4; o4.x = p; o4.y = p + v.x; o4.z = p + v.x + v.y; o4.w = p + v.x + v.y + v.z;
        *(int4*)&out[i0] = o4;
    } else {
        int pp = p;
        if (i0 < n)     { out[i0] = pp;     pp += v.x; }
        if (i0 + 1 < n) { out[i0 + 1] = pp; pp += v.y; }
        if (i0 + 2 < n) { out[i0 + 2] = pp; }
    }
    if (t == 0) bsum[blockIdx.x] = wsum[15];
}
__global__ void k_scanB(int* __restrict__ bsum, int nb, int* __restrict__ total) {
    int lane = threadIdx.x;
    int v = (lane < nb) ? bsum[lane] : 0;
    int s = v;
#pragma unroll
    for (int o = 1; o < 64; o <<= 1) { int u = __shfl_up(s, o, 64); if (lane >= o) s += u; }
    if (lane < nb) bsum[lane] = s - v;
    if (lane == 63) total[0] = s;
}
__global__ void k_scanC(int* __restrict__ rowptr, int* __restrict__ cursor,
                        const int* __restrict__ boff, int n) {
    int i = blockIdx.x * 256 + threadIdx.x;
    if (i < n) {
        int r = rowptr[i] + boff[i >> 12];
        rowptr[i] = r; cursor[i] = r;
    }
}
__global__ void k_scatter(const int* __restrict__ srcp, const int* __restrict__ dstp, int E,
                          int* __restrict__ cursor, int* __restrict__ col) {
    int e = blockIdx.x * 256 + threadIdx.x;
    if (e < E) {
        int p = atomicAdd(&cursor[dstp[e]], 1);
        col[p] = srcp[e];
    }
}

// ---------- fused: input proj + prelu0 + conv1 lin + att scalars ----------
// v5 (champion, 45.7us / total 318.9): BOTH W and A staged via global_load_lds
// with coalesced sources. A chunk = 16 coalesced glds (8 W + 8 A) -> one drain ->
// LDS-local compute. sh (phase-2 h-tile) ALIASES sA (dead after chunk 3).
// LDS 64KB -> 2 blk/CU. R6 (pipeline) and R7 (barrier-free) both regressed;
// this design point is the measured minimum of the 7-structure sweep.
__global__ __launch_bounds__(256) void k_fused1(
    const float* __restrict__ x, const float* __restrict__ numx, const float* __restrict__ numm,
    const float* __restrict__ txt, const float* __restrict__ txtm,
    const float* __restrict__ numw, const float* __restrict__ numb,
    const float* __restrict__ txtb, const float* __restrict__ nodeb,
    const float* __restrict__ pa,
    const u16* __restrict__ txtwb, const u16* __restrict__ nodewb, const u16* __restrict__ w1b,
    const float* __restrict__ atts, const float* __restrict__ attd,
    u16* __restrict__ xh, float* __restrict__ asrc, float* __restrict__ adst) {
    __shared__ u16 swl[128 * 128];          // linear weight tile (glds dst)
    __shared__ float sA[4][2048];           // per-wave A tile [16][128] f32 (glds dst)
    int tid = threadIdx.x, w = tid >> 6, lane = tid & 63, quad = lane >> 4, l16 = lane & 15;
    int nb = blockIdx.x * 64 + w * 16;

    float* sAw = &sA[w][0];
    u16* shw = (u16*)sAw;                   // phase-2 h-tile aliases sA (4KB of 8KB)
    const float* tBase = txt + (size_t)nb * 384;
    const float* xBase = x + (size_t)nb * 128;

    f32x4 acc[8];
#pragma unroll
    for (int ct = 0; ct < 8; ++ct) { f32x4 z = {0.f, 0.f, 0.f, 0.f}; acc[ct] = z; }

#define CHUNK(Wp, ldk, koff, Ab)                                                \
    {                                                                           \
        stageW_glds(Wp, ldk, koff, swl, tid);                                   \
        stageA_glds(Ab, ldk, koff, sAw, lane);                                  \
        __syncthreads(); /* vmcnt(0): W+A landed */                             \
        _Pragma("unroll")                                                       \
        for (int ks = 0; ks < 4; ++ks) {                                        \
            int s0 = (ks * 8 + quad * 2) ^ (l16 & 7);                           \
            int s1 = (ks * 8 + quad * 2 + 1) ^ (l16 & 7);                       \
            float4 fa = *(const float4*)&sAw[l16 * 128 + s0 * 4];               \
            float4 fb = *(const float4*)&sAw[l16 * 128 + s1 * 4];               \
            bf16x8 a0 = cvt8(fa, fb);                                           \
            _Pragma("unroll")                                                   \
            for (int ct = 0; ct < 8; ++ct)                                      \
                acc[ct] = __builtin_amdgcn_mfma_f32_16x16x32_bf16(              \
                    a0, ldBx(swl, ct, ks, l16, quad), acc[ct], 0, 0, 0);        \
        }                                                                       \
        __syncthreads(); /* all waves done with swl/sA */                       \
    }

    CHUNK(txtwb, 384, 0,   tBase)
    CHUNK(txtwb, 384, 128, tBase)
    CHUNK(txtwb, 384, 256, tBase)
    // scale txt contribution by txt_mask
#pragma unroll
    for (int r = 0; r < 4; ++r) {
        float tm = txtm[nb + quad * 4 + r];
#pragma unroll
        for (int ct = 0; ct < 8; ++ct) acc[ct][r] *= tm;
    }
    CHUNK(nodewb, 128, 0, xBase)
#undef CHUNK

    // epilogue 1: num term + biases + prelu -> per-wave swizzled h-tile [16][128] bf16
    // (aliases sA; this wave's sA reads are complete — acc depends on them)
    float nm[4];
#pragma unroll
    for (int r = 0; r < 4; ++r) {
        int n = nb + quad * 4 + r;
        nm[r] = numx[n] * numm[n];
    }
#pragma unroll
    for (int ct = 0; ct < 8; ++ct) {
        int c = ct * 16 + l16;
        float cw = numw[c];
        float cb = numb[c] + txtb[c] + nodeb[c];
        float pav = pa[c];
#pragma unroll
        for (int r = 0; r < 4; ++r) {
            float v = acc[ct][r] + nm[r] * cw + cb;
            v = v >= 0.f ? v : pav * v;
            int rr = quad * 4 + r;
            int ps = (c >> 3) ^ (rr & 7);               // swizzled 16B slot
            shw[rr * 128 + ps * 8 + (c & 7)] = f2bf(v);
        }
    }
    // phase 2: xh = h0 @ W1^T  (A-frags from shw, swizzled b128 reads)
    __syncthreads();                     // all waves done reading swl (chunk 3) + sh written
    stageW_glds(w1b, 128, 0, swl, tid);
    __syncthreads();                     // vmcnt(0): W1 staged
    f32x4 a2[8];
#pragma unroll
    for (int ct = 0; ct < 8; ++ct) { f32x4 z = {0.f, 0.f, 0.f, 0.f}; a2[ct] = z; }
#pragma unroll
    for (int ks = 0; ks < 4; ++ks) {
        bf16x8 a0 = ld16B(shw, l16 * 128 + (((ks * 4 + quad) ^ (l16 & 7)) << 3));
#pragma unroll
        for (int ct = 0; ct < 8; ++ct)
            a2[ct] = __builtin_amdgcn_mfma_f32_16x16x32_bf16(
                a0, ldBx(swl, ct, ks, l16, quad), a2[ct], 0, 0, 0);
    }
    // epilogue 2: store xh + attention scalars (R9-proven reduction)
#pragma unroll
    for (int ct = 0; ct < 8; ++ct) {
        int c = ct * 16 + l16;
#pragma unroll
        for (int r = 0; r < 4; ++r)
            xh[(size_t)(nb + quad * 4 + r) * 128 + c] = f2bf(a2[ct][r]);
    }
    float as_[8], ad_[8];
#pragma unroll
    for (int ct = 0; ct < 8; ++ct) {
        int c = ct * 16 + l16;
        as_[ct] = atts[c];
        ad_[ct] = attd[c];
    }
#pragma unroll
    for (int hh = 0; hh < 4; ++hh) {
        float vs[4], vd[4];
#pragma unroll
        for (int r = 0; r < 4; ++r) {
            vs[r] = a2[2 * hh][r] * as_[2 * hh] + a2[2 * hh + 1][r] * as_[2 * hh + 1];
            vd[r] = a2[2 * hh][r] * ad_[2 * hh] + a2[2 * hh + 1][r] * ad_[2 * hh + 1];
        }
#pragma unroll
        for (int o = 1; o <= 8; o <<= 1) {
#pragma unroll
            for (int r = 0; r < 4; ++r) {
                vs[r] += __shfl_xor(vs[r], o, 64);
                vd[r] += __shfl_xor(vd[r], o, 64);
            }
        }
        if ((l16 >> 2) == hh) {
            int r = l16 & 3;
            float ss = (r == 0) ? vs[0] : (r == 1) ? vs[1] : (r == 2) ? vs[2] : vs[3];
            float dd = (r == 0) ? vd[0] : (r == 1) ? vd[1] : (r == 2) ? vd[2] : vd[3];
            int n = nb + quad * 4 + r;
            asrc[n * 4 + hh] = ss;
            adst[n * 4 + hh] = dd;
        }
    }
}

// ---------- xh = h @ W^T (MFMA) + attention scalars. v4: glds W + named A regs ----------
__global__ __launch_bounds__(256) void k_xh(
    const u16* __restrict__ h, const u16* __restrict__ Wb,
    const float* __restrict__ att_s, const float* __restrict__ att_d,
    u16* __restrict__ xh, float* __restrict__ asrc, float* __restrict__ adst) {
    __shared__ u16 swl[128 * 128];
    int tid = threadIdx.x;
    int w = tid >> 6, lane = tid & 63, quad = lane >> 4, l16 = lane & 15;
    int nb = blockIdx.x * 64 + w * 16;

    stageW_glds(Wb, 128, 0, swl, tid);              // async, zero VGPR
    const u16* hrow = h + (size_t)(nb + l16) * 128 + quad * 8;
    uint4 A0 = *(const uint4*)(hrow);
    uint4 A1 = *(const uint4*)(hrow + 32);
    uint4 A2 = *(const uint4*)(hrow + 64);
    uint4 A3 = *(const uint4*)(hrow + 96);
    f32x4 acc[8];
#pragma unroll
    for (int ct = 0; ct < 8; ++ct) { f32x4 z = {0.f, 0.f, 0.f, 0.f}; acc[ct] = z; }
    __syncthreads();                                // vmcnt(0): W staged, A in regs
    union { uint4 u; bf16x8 b; } t0, t1, t2, t3;
    t0.u = A0; t1.u = A1; t2.u = A2; t3.u = A3;
#pragma unroll
    for (int ct = 0; ct < 8; ++ct)
        acc[ct] = __builtin_amdgcn_mfma_f32_16x16x32_bf16(
            t0.b, ldBx(swl, ct, 0, l16, quad), acc[ct], 0, 0, 0);
#pragma unroll
    for (int ct = 0; ct < 8; ++ct)
        acc[ct] = __builtin_amdgcn_mfma_f32_16x16x32_bf16(
            t1.b, ldBx(swl, ct, 1, l16, quad), acc[ct], 0, 0, 0);
#pragma unroll
    for (int ct = 0; ct < 8; ++ct)
        acc[ct] = __builtin_amdgcn_mfma_f32_16x16x32_bf16(
            t2.b, ldBx(swl, ct, 2, l16, quad), acc[ct], 0, 0, 0);
#pragma unroll
    for (int ct = 0; ct < 8; ++ct)
        acc[ct] = __builtin_amdgcn_mfma_f32_16x16x32_bf16(
            t3.b, ldBx(swl, ct, 3, l16, quad), acc[ct], 0, 0, 0);
#pragma unroll
    for (int ct = 0; ct < 8; ++ct) {
        int c = ct * 16 + l16;
#pragma unroll
        for (int r = 0; r < 4; ++r) {
            int n = nb + quad * 4 + r;
            xh[(size_t)n * 128 + c] = f2bf(acc[ct][r]);
        }
    }
    float as_[8], ad_[8];
#pragma unroll
    for (int ct = 0; ct < 8; ++ct) {
        int c = ct * 16 + l16;
        as_[ct] = att_s[c];
        ad_[ct] = att_d[c];
    }
#pragma unroll
    for (int hh = 0; hh < 4; ++hh) {
        float vs[4], vd[4];
#pragma unroll
        for (int r = 0; r < 4; ++r) {
            vs[r] = acc[2 * hh][r] * as_[2 * hh] + acc[2 * hh + 1][r] * as_[2 * hh + 1];
            vd[r] = acc[2 * hh][r] * ad_[2 * hh] + acc[2 * hh + 1][r] * ad_[2 * hh + 1];
        }
#pragma unroll
        for (int o = 1; o <= 8; o <<= 1) {
#pragma unroll
            for (int r = 0; r < 4; ++r) {
                vs[r] += __shfl_xor(vs[r], o, 64);
                vd[r] += __shfl_xor(vd[r], o, 64);
            }
        }
        if ((l16 >> 2) == hh) {
            int r = l16 & 3;
            float ss = (r == 0) ? vs[0] : (r == 1) ? vs[1] : (r == 2) ? vs[2] : vs[3];
            float dd = (r == 0) ? vd[0] : (r == 1) ? vd[1] : (r == 2) ? vd[2] : vd[3];
            int n = nb + quad * 4 + r;
            asrc[n * 4 + hh] = ss;
            adst[n * 4 + hh] = dd;
        }
    }
}

// ---------- per-dst softmax + aggregation + bias + LN + prelu (+ head) ----------
// v2: 8-deep unrolled serial gather (8 loads in flight; avg degree 16 -> 2 rounds).
__global__ __launch_bounds__(64) void k_agg(
    const u16* __restrict__ xh, const float* __restrict__ asrc, const float* __restrict__ adst,
    const int* __restrict__ rowptr, const int* __restrict__ col,
    const float* __restrict__ bias, const float* __restrict__ g, const float* __restrict__ b,
    const float* __restrict__ pa, u16* __restrict__ hnext,
    const float* __restrict__ outw, const float* __restrict__ outb, float* __restrict__ outy,
    int is_final) {
    __shared__ int   scol[64];
    __shared__ float scoef[64][4];
    int n = blockIdx.x, lane = threadIdx.x;
    int beg = rowptr[n], end = rowptr[n + 1];
    const float4* asrc4 = (const float4*)asrc;

    float4 adv = ((const float4*)adst)[n];
    float ad[4] = { adv.x, adv.y, adv.z, adv.w };
    float4 asv = asrc4[n];
    float els[4];
#pragma unroll
    for (int h = 0; h < 4; h++) {
        float a = ((const float*)&asv)[h] + ad[h];
        a = a >= 0.f ? a : 0.2f * a;
        els[h] = __expf(a);
    }
    int hh = lane >> 4;
    u32 vself = ((const u32*)(xh + (size_t)n * 128))[lane];
    float ac0[8], ac1[8];
#pragma unroll
    for (int q = 0; q < 8; ++q) { ac0[q] = 0.f; ac1[q] = 0.f; }
    ac0[0] = els[hh] * bf2f(vself & 0xffffu);
    ac1[0] = els[hh] * bf2f(vself >> 16);
    float l[4] = { 0.f, 0.f, 0.f, 0.f };

    for (int base = beg; base < end; base += 64) {
        int e = base + lane;
        int cnt = min(64, end - base);
        if (e < end) {
            int s = col[e];
            float4 av = asrc4[s];
            scol[lane] = s;
            float cf[4];
#pragma unroll
            for (int h = 0; h < 4; h++) {
                float a = ((const float*)&av)[h] + ad[h];
                a = a >= 0.f ? a : 0.2f * a;
                cf[h] = __expf(a);
                l[h] += cf[h];
            }
            *(float4*)scoef[lane] = make_float4(cf[0], cf[1], cf[2], cf[3]);
        }
        __syncthreads();
        int j = 0;
        for (; j + 7 < cnt; j += 8) {
            int ss[8]; float cc[8]; u32 vv[8];
#pragma unroll
            for (int q = 0; q < 8; ++q) { ss[q] = scol[j + q]; cc[q] = scoef[j + q][hh]; }
#pragma unroll
            for (int q = 0; q < 8; ++q) vv[q] = ((const u32*)(xh + (size_t)ss[q] * 128))[lane];
#pragma unroll
            for (int q = 0; q < 8; ++q) {
                ac0[q] += cc[q] * bf2f(vv[q] & 0xffffu);
                ac1[q] += cc[q] * bf2f(vv[q] >> 16);
            }
        }
        for (; j + 3 < cnt; j += 4) {
            int ss[4]; float cc[4]; u32 vv[4];
#pragma unroll
            for (int q = 0; q < 4; ++q) { ss[q] = scol[j + q]; cc[q] = scoef[j + q][hh]; }
#pragma unroll
            for (int q = 0; q < 4; ++q) vv[q] = ((const u32*)(xh + (size_t)ss[q] * 128))[lane];
#pragma unroll
            for (int q = 0; q < 4; ++q) {
                ac0[q] += cc[q] * bf2f(vv[q] & 0xffffu);
                ac1[q] += cc[q] * bf2f(vv[q] >> 16);
            }
        }
        for (; j < cnt; ++j) {
            int s0 = scol[j];
            float c0 = scoef[j][hh];
            u32 v0 = ((const u32*)(xh + (size_t)s0 * 128))[lane];
            ac0[0] += c0 * bf2f(v0 & 0xffffu);
            ac1[0] += c0 * bf2f(v0 >> 16);
        }
        __syncthreads();
    }
    float acc0 = 0.f, acc1 = 0.f;
#pragma unroll
    for (int q = 0; q < 8; ++q) { acc0 += ac0[q]; acc1 += ac1[q]; }

    float L[4];
#pragma unroll
    for (int h = 0; h < 4; h++) L[h] = wred_sum(l[h]) + els[h];
    float inv = 1.f / L[hh];
    acc0 *= inv;
    acc1 *= inv;

    int c0i = 2 * lane;
    float2 bi = *(const float2*)(bias + c0i);
    acc0 += bi.x; acc1 += bi.y;

    float mean = wred_sum(acc0 + acc1) * (1.f / 128.f);
    float d0 = acc0 - mean, d1 = acc1 - mean;
    float var = wred_sum(d0 * d0 + d1 * d1) * (1.f / 128.f);
    float rstd = rsqrtf(var + 1e-5f);
    float2 gg = *(const float2*)(g + c0i);
    float2 bb = *(const float2*)(b + c0i);
    float2 pp = *(const float2*)(pa + c0i);
    float y0 = d0 * rstd * gg.x + bb.x;
    float y1 = d1 * rstd * gg.y + bb.y;
    y0 = y0 >= 0.f ? y0 : pp.x * y0;
    y1 = y1 >= 0.f ? y1 : pp.y * y1;

    if (is_final) {
        float2 ow = *(const float2*)(outw + c0i);
        float dot = wred_sum(y0 * ow.x + y1 * ow.y);
        if (lane == 0) outy[n] = dot + outb[0];
    } else {
        ((u32*)(hnext + (size_t)n * 128))[lane] = (u32)f2bf(y0) | ((u32)f2bf(y1) << 16);
    }
}

// ---------- launch ----------
extern "C" void kernel_launch(void* const* d_in, const int* in_sizes, int n_in,
                              void* d_out, int out_size, void* d_ws, size_t ws_size,
                              hipStream_t stream) {
    const int N = in_sizes[2];          // num_mask has N elements
    const int E = in_sizes[5] / 2;      // edge_index is [2,E]

    const float* x      = (const float*)d_in[0];
    const float* numx   = (const float*)d_in[1];
    const float* numm   = (const float*)d_in[2];
    const float* txt    = (const float*)d_in[3];
    const float* txtm   = (const float*)d_in[4];
    const int*   ei     = (const int*)d_in[5];
    const float* numw   = (const float*)d_in[6];
    const float* numb   = (const float*)d_in[7];
    const float* txtw   = (const float*)d_in[8];
    const float* txtb   = (const float*)d_in[9];
    const float* nodew  = (const float*)d_in[10];
    const float* nodeb  = (const float*)d_in[11];
    const float* pa0    = (const float*)d_in[12];
    const float* conv1w = (const float*)d_in[13];
    const float* atts1  = (const float*)d_in[14];
    const float* attd1  = (const float*)d_in[15];
    const float* bias1  = (const float*)d_in[16];
    const float* g1     = (const float*)d_in[17];
    const float* b1     = (const float*)d_in[18];
    const float* pa1    = (const float*)d_in[19];
    const float* conv2w = (const float*)d_in[20];
    const float* atts2  = (const float*)d_in[21];
    const float* attd2  = (const float*)d_in[22];
    const float* bias2  = (const float*)d_in[23];
    const float* g2     = (const float*)d_in[24];
    const float* b2     = (const float*)d_in[25];
    const float* pa2    = (const float*)d_in[26];
    const float* outw   = (const float*)d_in[27];
    const float* outb   = (const float*)d_in[28];

    const int* srcp = ei;
    const int* dstp = ei + E;

    const int szTxtw = in_sizes[8];     // 128*384
    const int szNode = in_sizes[10];    // 128*128
    const int szW1   = in_sizes[13];
    const int szW2   = in_sizes[20];
    const int szWAll = szTxtw + szNode + szW1 + szW2;

    char* p = (char*)d_ws;
    auto alloc = [&](size_t bytes) -> void* {
        void* q = (void*)p;
        p += (bytes + 255) & ~(size_t)255;
        return q;
    };
    u16*   hA     = (u16*)alloc((size_t)N * 128 * 2);   // h1 (bf16)
    u16*   hB     = (u16*)alloc((size_t)N * 128 * 2);   // xh1 / xh2 (bf16)
    float* asrc   = (float*)alloc((size_t)N * 4 * 4);
    float* adst   = (float*)alloc((size_t)N * 4 * 4);
    int*   deg    = (int*)alloc((size_t)N * 4);
    int*   rowptr = (int*)alloc((size_t)(N + 1) * 4);
    int*   cursor = (int*)alloc((size_t)N * 4);
    int*   col    = (int*)alloc((size_t)E * 4);
    int*   bsum   = (int*)alloc(64 * 4);
    u16*   wbf    = (u16*)alloc((size_t)szWAll * 2);    // bf16 weights [txtw|nodew|W1|W2]

    u16* txtwb  = wbf;
    u16* nodewb = wbf + szTxtw;
    u16* w1b    = nodewb + szNode;
    u16* w2b    = w1b + szW1;

    // one-time weight conversion + deg zeroing (merged; ordered before k_hist)
    const int gCvt = ((szWAll / 8 > N ? szWAll / 8 : N) + 255) / 256;
    k_cvtw<<<gCvt, 256, 0, stream>>>(
        txtw, nodew, conv1w, conv2w, wbf, szTxtw, szNode, szW1, szW2, deg, N);

    // CSR by dst (self-loops handled analytically in k_agg)
    const int nbScan = (N + 4095) / 4096;
    k_hist<<<(E + 255) / 256, 256, 0, stream>>>(dstp, E, deg);
    k_scanA<<<nbScan, 1024, 0, stream>>>(deg, N, rowptr, bsum);
    k_scanB<<<1, 64, 0, stream>>>(bsum, nbScan, rowptr + N);
    k_scanC<<<(N + 255) / 256, 256, 0, stream>>>(rowptr, cursor, bsum, N);
    k_scatter<<<(E + 255) / 256, 256, 0, stream>>>(srcp, dstp, E, cursor, col);

    const int gProj = N / 64;   // 625 for N=40000

    // layer 1: fused input proj + prelu0 + conv1 lin (h0 never touches HBM)
    k_fused1<<<gProj, 256, 0, stream>>>(x, numx, numm, txt, txtm, numw, numb,
                                        txtb, nodeb, pa0,
                                        txtwb, nodewb, w1b, atts1, attd1, hB, asrc, adst);
    k_agg<<<N, 64, 0, stream>>>(hB, asrc, adst, rowptr, col, bias1, g1, b1, pa1,
                                hA, nullptr, nullptr, nullptr, 0);

    // layer 2
    k_xh<<<gProj, 256, 0, stream>>>(hA, w2b, atts2, attd2, hB, asrc, adst);
    k_agg<<<N, 64, 0, stream>>>(hB, asrc, adst, rowptr, col, bias2, g2, b2, pa2,
                                nullptr, outw, outb, (float*)d_out, 1);
}